// Round 1
// baseline (375.082 us; speedup 1.0000x reference)
//
#include <hip/hip_runtime.h>

#define T 32
#define C_IN 64
#define H 128
#define W 128
#define C_OUT 128
#define KH 5
#define KW 5
#define H_OUT 124
#define W_OUT 124
#define K_WINNERS 256
#define LR_PLUS 0.004f
#define LR_MINUS -0.003f

// ws layout: [0 .. C_OUT) int win_idx; [C_OUT .. 2*C_OUT) float out_val

// One block, 256 threads. Finds LAST winner index per filter (scan overwrite
// semantics => atomicMax over winner array position), then sums output_spikes
// over T at each winning (f, r, c).
__global__ void winner_prep(const float* __restrict__ out_spikes,
                            const int* __restrict__ winners,
                            int* __restrict__ win_idx,
                            float* __restrict__ out_val) {
    __shared__ int s_win[C_OUT];
    const int tid = threadIdx.x;
    if (tid < C_OUT) s_win[tid] = -1;
    __syncthreads();
    if (tid < K_WINNERS) {
        int f = winners[tid * 3];
        atomicMax(&s_win[f], tid);
    }
    __syncthreads();
    if (tid < C_OUT) {
        int k = s_win[tid];
        win_idx[tid] = k;
        float v = 0.0f;
        if (k >= 0) {
            int r = winners[k * 3 + 1];
            int c = winners[k * 3 + 2];
            const float* p = out_spikes + (size_t)tid * (H_OUT * W_OUT)
                                        + (size_t)r * W_OUT + c;
            #pragma unroll
            for (int t = 0; t < T; ++t)
                v += p[(size_t)t * (C_OUT * H_OUT * W_OUT)];
        }
        out_val[tid] = v;
    }
}

// One thread per weight element (f, ci, kh, kw). 1600 elements per filter
// = exactly 25 waves, so the per-filter branch is wave-uniform.
__global__ void stdp_update(const float* __restrict__ in_spikes,
                            const int* __restrict__ winners,
                            const float* __restrict__ weight,
                            const int* __restrict__ win_idx,
                            const float* __restrict__ out_val,
                            float* __restrict__ out) {
    const int idx = blockIdx.x * blockDim.x + threadIdx.x;  // grid sized exactly
    const int f   = idx / (C_IN * KH * KW);
    const int rem = idx % (C_IN * KH * KW);
    const int ci  = rem / (KH * KW);
    const int p   = rem % (KH * KW);
    const int kh  = p / KW;
    const int kw  = p % KW;

    float w = weight[idx];
    int k = win_idx[f];
    float res;
    if (k < 0) {
        res = w;  // lr = 0: weight unchanged
    } else {
        int r = winners[k * 3 + 1] + kh;   // r in [0,124) + kh<5 => < 128, in-bounds
        int c = winners[k * 3 + 2] + kw;
        const float* ptr = in_spikes + (size_t)ci * (H * W) + (size_t)r * W + c;
        float sum = 0.0f;
        #pragma unroll
        for (int t = 0; t < T; ++t)
            sum += ptr[(size_t)t * (C_IN * H * W)];
        float lr = (sum >= out_val[f]) ? LR_PLUS : LR_MINUS;
        res = w + lr * w * (1.0f - w);
    }
    res = fminf(fmaxf(res, 0.0f), 1.0f);
    out[idx] = res;
}

extern "C" void kernel_launch(void* const* d_in, const int* in_sizes, int n_in,
                              void* d_out, int out_size, void* d_ws, size_t ws_size,
                              hipStream_t stream) {
    const float* in_spikes  = (const float*)d_in[0];  // (T, C_IN, H, W)
    const float* out_spikes = (const float*)d_in[1];  // (T, C_OUT, H_OUT, W_OUT)
    const float* weight     = (const float*)d_in[2];  // (C_OUT, C_IN, KH, KW)
    const int*   winners    = (const int*)d_in[3];    // (K_WINNERS, 3)
    float* out = (float*)d_out;

    int*   win_idx = (int*)d_ws;
    float* out_val = (float*)((char*)d_ws + C_OUT * sizeof(int));

    winner_prep<<<1, 256, 0, stream>>>(out_spikes, winners, win_idx, out_val);

    const int total = C_OUT * C_IN * KH * KW;  // 204800 = 800 * 256 exactly
    stdp_update<<<total / 256, 256, 0, stream>>>(in_spikes, winners, weight,
                                                 win_idx, out_val, out);
}

// Round 2
// 365.161 us; speedup vs baseline: 1.0272x; 1.0272x over previous
//
#include <hip/hip_runtime.h>

#define T 32
#define C_IN 64
#define H 128
#define W 128
#define C_OUT 128
#define KH 5
#define KW 5
#define H_OUT 124
#define W_OUT 124
#define K_WINNERS 256
#define LR_PLUS 0.004f
#define LR_MINUS -0.003f

#define BLOCKS_PER_F 5
#define BLOCK 320  // 5 waves; BLOCKS_PER_F*BLOCK = 1600 = C_IN*KH*KW exactly

// One fused kernel. 5 blocks per filter; filter index is block-uniform so the
// winner/no-winner branch never diverges within a wave. Each block:
//   1. scans winners (256 entries) for the LAST k with winners[k][0]==f
//      (scan-overwrite semantics of the reference => atomicMax on k),
//   2. sums output_spikes over T at that winner's (f,r,c) -> s_outval,
//   3. each thread gathers its weight element's input patch sum over T and
//      applies the STDP update. Spike sums are exact small integers in fp32,
//      so the >= comparison is bit-exact vs the reference.
__global__ __launch_bounds__(BLOCK) void stdp_fused(
        const float* __restrict__ in_spikes,
        const float* __restrict__ out_spikes,
        const float* __restrict__ weight,
        const int* __restrict__ winners,
        float* __restrict__ out) {
    __shared__ int s_k;
    __shared__ float s_part[T];
    __shared__ float s_outval;

    const int f = blockIdx.x / BLOCKS_PER_F;
    const int tid = threadIdx.x;

    if (tid == 0) s_k = -1;
    __syncthreads();
    if (tid < K_WINNERS && winners[tid * 3] == f)
        atomicMax(&s_k, tid);
    __syncthreads();
    const int k = s_k;

    int r0 = 0, c0 = 0;
    if (k >= 0) {
        r0 = winners[k * 3 + 1];  // block-uniform address -> broadcast load
        c0 = winners[k * 3 + 2];
        if (tid < T) {
            s_part[tid] = out_spikes[(size_t)tid * (C_OUT * H_OUT * W_OUT)
                                     + (size_t)f * (H_OUT * W_OUT)
                                     + (size_t)r0 * W_OUT + c0];
        }
    }
    __syncthreads();
    if (k >= 0 && tid == 0) {
        float v = 0.0f;
        #pragma unroll
        for (int t = 0; t < T; ++t) v += s_part[t];
        s_outval = v;
    }
    __syncthreads();

    const int rem = (blockIdx.x % BLOCKS_PER_F) * BLOCK + tid;  // 0..1599
    const int idx = f * (C_IN * KH * KW) + rem;
    float w = weight[idx];
    float res;
    if (k < 0) {
        res = w;  // lr == 0: weight unchanged (clip is no-op for w in [0,1])
    } else {
        const int ci = rem / (KH * KW);
        const int p  = rem % (KH * KW);
        const int r  = r0 + p / KW;   // < 124 + 4 < 128: in bounds
        const int c  = c0 + p % KW;
        const float* ptr = in_spikes + (size_t)ci * (H * W) + (size_t)r * W + c;
        float sum = 0.0f;
        #pragma unroll
        for (int t = 0; t < T; ++t)
            sum += ptr[(size_t)t * (C_IN * H * W)];  // 32 independent loads, pipelined
        float lr = (sum >= s_outval) ? LR_PLUS : LR_MINUS;
        res = w + lr * w * (1.0f - w);
    }
    out[idx] = fminf(fmaxf(res, 0.0f), 1.0f);
}

extern "C" void kernel_launch(void* const* d_in, const int* in_sizes, int n_in,
                              void* d_out, int out_size, void* d_ws, size_t ws_size,
                              hipStream_t stream) {
    const float* in_spikes  = (const float*)d_in[0];  // (T, C_IN, H, W)
    const float* out_spikes = (const float*)d_in[1];  // (T, C_OUT, H_OUT, W_OUT)
    const float* weight     = (const float*)d_in[2];  // (C_OUT, C_IN, KH, KW)
    const int*   winners    = (const int*)d_in[3];    // (K_WINNERS, 3)
    float* out = (float*)d_out;

    stdp_fused<<<C_OUT * BLOCKS_PER_F, BLOCK, 0, stream>>>(
        in_spikes, out_spikes, weight, winners, out);
}